// Round 5
// baseline (272.918 us; speedup 1.0000x reference)
//
#include <hip/hip_runtime.h>
#include <stdint.h>

typedef unsigned short u16;
typedef __attribute__((ext_vector_type(4))) float f32x4;
typedef __attribute__((ext_vector_type(16))) float f32x16;
typedef __attribute__((ext_vector_type(8))) short bf16x8;
typedef __attribute__((ext_vector_type(4))) unsigned short u16x4;
typedef __attribute__((ext_vector_type(4))) unsigned u32x4;

static __device__ __forceinline__ u16 f2bf(float f) {
  union { float f; unsigned u; } v; v.f = f;
  unsigned r = v.u + 0x7fffu + ((v.u >> 16) & 1u);
  return (u16)(r >> 16);
}

static __device__ __forceinline__ unsigned cvtpk(float lo, float hi) {
  unsigned r;
  asm("v_cvt_pk_bf16_f32 %0, %1, %2" : "=v"(r) : "v"(lo), "v"(hi));
  return r;
}

static __device__ __forceinline__ void plane32_swap(unsigned& a, unsigned& b) {
  asm volatile("v_permlane32_swap_b32 %0, %1" : "+v"(a), "+v"(b));
}

static __device__ __forceinline__ void load_lds16(const void* g, void* l) {
  __builtin_amdgcn_global_load_lds(
      (const __attribute__((address_space(1))) void*)g,
      (__attribute__((address_space(3))) void*)l, 16, 0, 0);
}

// ---------------- conversion kernels ----------------

__global__ __launch_bounds__(256) void cvt_f32_bf16(
    const float* __restrict__ in, u16* __restrict__ out, int n) {
  int i = blockIdx.x * 256 + threadIdx.x;
  const int n4 = n >> 2;
  for (; i < n4; i += gridDim.x * 256) {
    f32x4 v = *(const f32x4*)(in + (size_t)i * 4);
    u16x4 o = { f2bf(v[0]), f2bf(v[1]), f2bf(v[2]), f2bf(v[3]) };
    *(u16x4*)(out + (size_t)i * 4) = o;
  }
}

__global__ __launch_bounds__(256) void build_wcat(
    const float* __restrict__ Wq, const float* __restrict__ Wk,
    const float* __restrict__ Wv, u16* __restrict__ out) {
  int i = blockIdx.x * 256 + threadIdx.x;
  const int n4 = 3072 * 512;
  for (; i < n4; i += gridDim.x * 256) {
    int row = i >> 9;
    int c4 = i & 511;
    const float* src;
    if (row < 2048)       src = Wq + (size_t)row * 2048;
    else if (row < 2560)  src = Wk + (size_t)(row - 2048) * 2048;
    else                  src = Wv + (size_t)(row - 2560) * 2048;
    f32x4 v = *(const f32x4*)(src + c4 * 4);
    u16x4 o = { f2bf(v[0]), f2bf(v[1]), f2bf(v[2]), f2bf(v[3]) };
    *(u16x4*)(out + (size_t)i * 4) = o;
  }
}

// ---------------- bf16 bt-GEMM, 256x256 8-phase counted-vmcnt: C = A[M,K] B[N,K]^T --------
// 8 waves (2M x 4N), BK=64 in two 32-K halves. LDS slots [4 kc][256 row][8] (conflict-free
// ds_read_b128, linear global_load_lds dest). Stage ptr runs 6 half-slots ahead; vmcnt(8)
// at end of odd phases (exact FIFO: needed slots complete before the closing barrier).
__global__ __launch_bounds__(512, 2) void gemm256(
    const u16* __restrict__ A, const u16* __restrict__ B,
    float* __restrict__ C, int M, int N, int K) {
  __shared__ u16 S[65536];  // 2 buf x 4 slots x 8192 u16 = 128 KB
  const int nbn = N >> 8;
  const int nwg = (M >> 8) * nbn;
  const int chunk = nwg >> 3;  // requires nwg % 8 == 0
  const int bid = blockIdx.x;
  const int wg = (bid & 7) * chunk + (bid >> 3);
  const int bm = wg / nbn, bn = wg % nbn;
  const int tid = threadIdx.x;
  const int w = tid >> 6, l = tid & 63;
  const int wm = w >> 2, wn = w & 3;
  const int lr = l & 15, lg = l >> 4;
  const int NT = K >> 6;

  f32x4 acc[8][4] = {};
  bf16x8 af[8];

  // stage s: tile tau=s>>2 into buf tau&1; part p: 0=A kh0, 1=B kh0, 2=A kh1, 3=B kh1
  auto stage = [&](int s) {
    const int tau = s >> 2, p = s & 3;
    const u16* G = (p & 1) ? B : A;
    const int rbase = ((p & 1) ? bn : bm) << 8;
    const int col0 = tau * 64 + (p >> 1) * 32;
    u16* slot = S + ((((tau & 1) << 2) + p) << 13);
#pragma unroll
    for (int j = 0; j < 2; ++j) {
      const int o = (j << 12) + tid * 8;          // u16 offset in slot
      const int kc = o >> 11, row = (o >> 3) & 255;
      load_lds16(G + (size_t)(rbase + row) * K + col0 + kc * 8, slot + o);
    }
  };

  for (int s0 = 0; s0 < 6; ++s0) stage(s0);
  asm volatile("s_waitcnt vmcnt(8)" ::: "memory");  // stages 0,1 (tile0 A0,B0) done
  __builtin_amdgcn_s_barrier();

  int s = 6;
  for (int tau = 0; tau < NT - 2; ++tau) {
    const int buf = tau & 1;
#pragma unroll
    for (int q = 0; q < 4; ++q) {
      const int kh = q >> 1, nb = (q & 1) << 1;
      const u16* Sa = S + (((buf << 2) + kh * 2) << 13);
      const u16* Sb = Sa + 8192;
      if ((q & 1) == 0) {
#pragma unroll
        for (int m = 0; m < 8; ++m)
          af[m] = *(const bf16x8*)(Sa + ((lg * 256 + wm * 128 + m * 16 + lr) << 3));
      }
      bf16x8 b0 = *(const bf16x8*)(Sb + ((lg * 256 + wn * 64 + (nb + 0) * 16 + lr) << 3));
      bf16x8 b1 = *(const bf16x8*)(Sb + ((lg * 256 + wn * 64 + (nb + 1) * 16 + lr) << 3));
      stage(s++);
      if (q & 1) asm volatile("s_waitcnt vmcnt(8)" ::: "memory");
      __builtin_amdgcn_s_barrier();
      asm volatile("s_waitcnt lgkmcnt(0)" ::: "memory");
      __builtin_amdgcn_sched_barrier(0);
      __builtin_amdgcn_s_setprio(1);
#pragma unroll
      for (int m = 0; m < 8; ++m) {
        acc[m][nb + 0] = __builtin_amdgcn_mfma_f32_16x16x32_bf16(af[m], b0, acc[m][nb + 0], 0, 0, 0);
        acc[m][nb + 1] = __builtin_amdgcn_mfma_f32_16x16x32_bf16(af[m], b1, acc[m][nb + 1], 0, 0, 0);
      }
      __builtin_amdgcn_s_setprio(0);
      __builtin_amdgcn_s_barrier();
    }
  }
  // tail: last two half-slot stages, one drain, then barrier-free compute of 2 tiles
  stage(4 * NT - 2);
  stage(4 * NT - 1);
  asm volatile("s_waitcnt vmcnt(0)" ::: "memory");
  __builtin_amdgcn_s_barrier();
  for (int tau = NT - 2; tau < NT; ++tau) {
    const int buf = tau & 1;
#pragma unroll
    for (int q = 0; q < 4; ++q) {
      const int kh = q >> 1, nb = (q & 1) << 1;
      const u16* Sa = S + (((buf << 2) + kh * 2) << 13);
      const u16* Sb = Sa + 8192;
      if ((q & 1) == 0) {
#pragma unroll
        for (int m = 0; m < 8; ++m)
          af[m] = *(const bf16x8*)(Sa + ((lg * 256 + wm * 128 + m * 16 + lr) << 3));
      }
      bf16x8 b0 = *(const bf16x8*)(Sb + ((lg * 256 + wn * 64 + (nb + 0) * 16 + lr) << 3));
      bf16x8 b1 = *(const bf16x8*)(Sb + ((lg * 256 + wn * 64 + (nb + 1) * 16 + lr) << 3));
#pragma unroll
      for (int m = 0; m < 8; ++m) {
        acc[m][nb + 0] = __builtin_amdgcn_mfma_f32_16x16x32_bf16(af[m], b0, acc[m][nb + 0], 0, 0, 0);
        acc[m][nb + 1] = __builtin_amdgcn_mfma_f32_16x16x32_bf16(af[m], b1, acc[m][nb + 1], 0, 0, 0);
      }
    }
  }
  // epilogue
  const int rb = (bm << 8) + wm * 128 + lg * 4;
  const int cb = (bn << 8) + wn * 64 + lr;
#pragma unroll
  for (int m = 0; m < 8; ++m) {
#pragma unroll
    for (int nf = 0; nf < 4; ++nf) {
#pragma unroll
      for (int r = 0; r < 4; ++r)
        C[(size_t)(rb + m * 16 + r) * N + cb + nf * 16] = acc[m][nf][r];
    }
  }
}

// ---------------- bf16 bt-GEMM (m97 structure, 128^2) for GEMM2 ----------------

__global__ __launch_bounds__(256) void gemm_bt(
    const u16* __restrict__ A, const u16* __restrict__ B,
    float* __restrict__ C, int M, int N, int K) {
  __shared__ u16 As[128 * 32];
  __shared__ u16 Bs[128 * 32];
  const int tid = threadIdx.x;
  const int bm = blockIdx.y, bn = blockIdx.x;
  const int w = tid >> 6, l = tid & 63;
  const int wr = w >> 1, wc = w & 1;
  const int lr = l & 15, lg = l >> 4;
  f32x4 acc[4][4] = {};
  const int srow = tid >> 2;
  const int scol = (tid & 3) << 3;
  const u16* Ag = A + (size_t)bm * 128 * K + (size_t)srow * K + scol;
  const u16* Bg = B + (size_t)bn * 128 * K + (size_t)srow * K + scol;
  u16* Asl = As + srow * 32 + scol;
  u16* Bsl = Bs + srow * 32 + scol;
  const int nk = K >> 5;
  for (int kt = 0; kt < nk; ++kt) {
    __syncthreads();
    const int ko = kt << 5;
    load_lds16(Ag + ko, Asl);
    load_lds16(Ag + (size_t)64 * K + ko, Asl + 64 * 32);
    load_lds16(Bg + ko, Bsl);
    load_lds16(Bg + (size_t)64 * K + ko, Bsl + 64 * 32);
    __syncthreads();
    bf16x8 af[4], bfr[4];
#pragma unroll
    for (int m = 0; m < 4; ++m)
      af[m] = *(const bf16x8*)&As[(wr * 64 + m * 16 + lr) * 32 + lg * 8];
#pragma unroll
    for (int n = 0; n < 4; ++n)
      bfr[n] = *(const bf16x8*)&Bs[(wc * 64 + n * 16 + lr) * 32 + lg * 8];
#pragma unroll
    for (int m = 0; m < 4; ++m)
#pragma unroll
      for (int n = 0; n < 4; ++n)
        acc[m][n] = __builtin_amdgcn_mfma_f32_16x16x32_bf16(af[m], bfr[n], acc[m][n], 0, 0, 0);
  }
#pragma unroll
  for (int m = 0; m < 4; ++m) {
    const int row = bm * 128 + wr * 64 + m * 16 + lg * 4;
#pragma unroll
    for (int n = 0; n < 4; ++n) {
      const int col = bn * 128 + wc * 64 + n * 16 + lr;
#pragma unroll
      for (int r = 0; r < 4; ++r)
        C[(size_t)(row + r) * N + col] = acc[m][n][r];
    }
  }
}

// ---------------- per-head RMSNorm + RoPE ----------------
__global__ __launch_bounds__(256) void norm_rope(
    const float* __restrict__ qkv, const float* __restrict__ qn_w,
    const float* __restrict__ kn_w, const float* __restrict__ cosb,
    const float* __restrict__ sinb, u16* __restrict__ qhat,
    u16* __restrict__ khat) {
  const int gw = (blockIdx.x * 256 + threadIdx.x) >> 6;
  const int lane = threadIdx.x & 63;
  const int slot = gw % 20;
  const int row = gw / 20;  // b*2048 + t
  const int t = row & 2047;
  const int b = row >> 11;
  const float* src; const float* nw; u16* dst;
  bool isq = slot < 16;
  if (isq) {
    src = qkv + (size_t)row * 3072 + slot * 128;
    nw = qn_w;
    dst = qhat + ((size_t)(b * 16 + slot) * 2048 + t) * 128;
  } else {
    src = qkv + (size_t)row * 3072 + 2048 + (slot - 16) * 128;
    nw = kn_w;
    dst = khat + ((size_t)(b * 4 + (slot - 16)) * 2048 + t) * 128;
  }
  float x1 = src[lane], x2 = src[lane + 64];
  float ss = x1 * x1 + x2 * x2;
#pragma unroll
  for (int o = 32; o; o >>= 1) ss += __shfl_xor(ss, o);
  float rs = rsqrtf(ss * (1.0f / 128.0f) + 1e-6f);
  float h1 = x1 * rs * nw[lane];
  float h2 = x2 * rs * nw[lane + 64];
  float c = cosb[t * 128 + lane], s = sinb[t * 128 + lane];
  float o1 = h1 * c - h2 * s;
  float o2 = h2 * c + h1 * s;
  if (isq) { o1 *= 0.088388347648318447f; o2 *= 0.088388347648318447f; }
  dst[lane] = f2bf(o1);
  dst[lane + 64] = f2bf(o2);
}

// ---------------- V transpose: qkv fp32 [.,3072] v-cols -> vT bf16 [B,KV,D,T] ----------------
__global__ __launch_bounds__(256) void v_trans(
    const float* __restrict__ qkv, u16* __restrict__ vT) {
  __shared__ u16 st[64][130];
  const int bi = blockIdx.x;  // b*128 + kv*32 + tt
  const int tt = bi & 31;
  const int kv = (bi >> 5) & 3;
  const int b = bi >> 7;
  const int tid = threadIdx.x;
#pragma unroll
  for (int i = 0; i < 32; ++i) {
    int idx = i * 256 + tid;
    int t = idx >> 7, d = idx & 127;
    float v = qkv[(size_t)(b * 2048 + tt * 64 + t) * 3072 + 2560 + kv * 128 + d];
    st[t][d] = f2bf(v);
  }
  __syncthreads();
#pragma unroll
  for (int i = 0; i < 32; ++i) {
    int idx = i * 256 + tid;
    int d = idx >> 6, t = idx & 63;
    vT[((size_t)(b * 4 + kv) * 128 + d) * 2048 + tt * 64 + t] = st[t][d];
  }
}

// ---------------- causal GQA flash attention (swapped 32x32 QK^T, in-register softmax) ----
__global__ __launch_bounds__(256, 2) void attn(
    const u16* __restrict__ qhat, const u16* __restrict__ khat,
    const u16* __restrict__ vT, u16* __restrict__ yb) {
  __shared__ u16 Kt[2][64 * 128];
  const int bi = blockIdx.x;
  int bh, c;
  if (bi < 256) { bh = bi >> 3; c = bi & 7; }
  else          { bh = (bi - 256) >> 3; c = 15 - ((bi - 256) & 7); }
  const int h = bh & 15, b = bh >> 4;
  const int kvh = h >> 2;
  const int tid = threadIdx.x;
  const int w = tid >> 6, l = tid & 63;
  const int ql = l & 31;
  const int hi = l >> 5;
  const int q0 = c * 128;
  const int wq0 = q0 + w * 32;
  const int wq_end = wq0 + 31;
  const int qg = wq0 + ql;

  bf16x8 qf[8];
  const u16* qp = qhat + ((size_t)(b * 16 + h) * 2048 + qg) * 128 + hi * 8;
#pragma unroll
  for (int s = 0; s < 8; ++s) qf[s] = *(const bf16x8*)(qp + 16 * s);

  f32x16 yacc[4] = {};
  float m = -1e30f, lsum = 0.f;

  const u16* Kg = khat + (size_t)(b * 4 + kvh) * 2048 * 128;
  const u16* Vg = vT + (size_t)(b * 4 + kvh) * 128 * 2048;
  const int nt = 2 * c + 2;
  const int srow = tid >> 4, schunk = tid & 15;

#pragma unroll
  for (int cc = 0; cc < 4; ++cc) {
    int r = cc * 16 + srow;
    load_lds16(Kg + (size_t)r * 128 + (schunk ^ (r & 7)) * 8,
               &Kt[0][cc * 2048 + tid * 8]);
  }
  int cur = 0;
  for (int tile = 0; tile < nt; ++tile) {
    const int kv0 = tile * 64;
    __syncthreads();
    if (tile + 1 < nt) {
#pragma unroll
      for (int cc = 0; cc < 4; ++cc) {
        int r = cc * 16 + srow;
        load_lds16(Kg + (size_t)(kv0 + 64 + r) * 128 + (schunk ^ (r & 7)) * 8,
                   &Kt[cur ^ 1][cc * 2048 + tid * 8]);
      }
    }
    if (kv0 <= wq_end) {
      const u16* Vrow = Vg + (size_t)ql * 2048 + kv0 + hi * 8;
      bf16x8 va[4], vb[4];
#pragma unroll
      for (int ks = 0; ks < 4; ++ks) va[ks] = *(const bf16x8*)(Vrow + ks * 16);
#pragma unroll
      for (int ks = 0; ks < 4; ++ks) vb[ks] = *(const bf16x8*)(Vrow + 32 * 2048 + ks * 16);
      const u16* Kc = Kt[cur];
      f32x16 sacc[2] = {};
      __builtin_amdgcn_s_setprio(1);
#pragma unroll
      for (int n = 0; n < 2; ++n) {
#pragma unroll
        for (int s = 0; s < 8; ++s) {
          bf16x8 kf = *(const bf16x8*)&Kc[(n * 32 + ql) * 128 + (((2 * s + hi) ^ (l & 7)) * 8)];
          sacc[n] = __builtin_amdgcn_mfma_f32_32x32x16_bf16(kf, qf[s], sacc[n], 0, 0, 0);
        }
      }
      __builtin_amdgcn_s_setprio(0);
      if (kv0 + 63 > wq0) {
#pragma unroll
        for (int n = 0; n < 2; ++n)
#pragma unroll
          for (int r = 0; r < 16; ++r) {
            int kv = kv0 + n * 32 + (r & 3) + 8 * (r >> 2) + 4 * hi;
            if (kv > qg) sacc[n][r] = -1e30f;
          }
      }
      float pm = -1e30f;
#pragma unroll
      for (int n = 0; n < 2; ++n)
#pragma unroll
        for (int r = 0; r < 16; ++r) pm = fmaxf(pm, sacc[n][r]);
      pm = fmaxf(pm, __shfl_xor(pm, 32));
      if (!__all(pm - m <= 8.0f)) {
        float mn = fmaxf(m, pm);
        float sc = __expf(m - mn);
        m = mn;
        lsum *= sc;
#pragma unroll
        for (int r = 0; r < 16; ++r) {
          int row = (r & 3) + 8 * (r >> 2) + 4 * hi;
          float scr = __shfl(sc, row);
#pragma unroll
          for (int d = 0; d < 4; ++d) yacc[d][r] *= scr;
        }
      }
      float ls = 0.f;
#pragma unroll
      for (int n = 0; n < 2; ++n)
#pragma unroll
        for (int r = 0; r < 16; ++r) {
          float e = __expf(sacc[n][r] - m);
          sacc[n][r] = e;
          ls += e;
        }
      ls += __shfl_xor(ls, 32);
      lsum += ls;
      bf16x8 pa[4];
#pragma unroll
      for (int s4 = 0; s4 < 4; ++s4) {
        const int n = s4 >> 1, R = (s4 & 1) * 8;
        unsigned P01 = cvtpk(sacc[n][R + 0], sacc[n][R + 1]);
        unsigned P23 = cvtpk(sacc[n][R + 2], sacc[n][R + 3]);
        unsigned P45 = cvtpk(sacc[n][R + 4], sacc[n][R + 5]);
        unsigned P67 = cvtpk(sacc[n][R + 6], sacc[n][R + 7]);
        plane32_swap(P01, P45);
        plane32_swap(P23, P67);
        union { u32x4 u; bf16x8 bv; } cvu;
        cvu.u[0] = P01; cvu.u[1] = P23; cvu.u[2] = P45; cvu.u[3] = P67;
        pa[s4] = cvu.bv;
      }
      __builtin_amdgcn_s_setprio(1);
#pragma unroll
      for (int ks = 0; ks < 4; ++ks)
        yacc[0] = __builtin_amdgcn_mfma_f32_32x32x16_bf16(pa[ks], va[ks], yacc[0], 0, 0, 0);
#pragma unroll
      for (int ks = 0; ks < 4; ++ks) va[ks] = *(const bf16x8*)(Vrow + 64 * 2048 + ks * 16);
#pragma unroll
      for (int ks = 0; ks < 4; ++ks)
        yacc[1] = __builtin_amdgcn_mfma_f32_32x32x16_bf16(pa[ks], vb[ks], yacc[1], 0, 0, 0);
#pragma unroll
      for (int ks = 0; ks < 4; ++ks) vb[ks] = *(const bf16x8*)(Vrow + 96 * 2048 + ks * 16);
#pragma unroll
      for (int ks = 0; ks < 4; ++ks)
        yacc[2] = __builtin_amdgcn_mfma_f32_32x32x16_bf16(pa[ks], va[ks], yacc[2], 0, 0, 0);
#pragma unroll
      for (int ks = 0; ks < 4; ++ks)
        yacc[3] = __builtin_amdgcn_mfma_f32_32x32x16_bf16(pa[ks], vb[ks], yacc[3], 0, 0, 0);
      __builtin_amdgcn_s_setprio(0);
    }
    cur ^= 1;
  }
#pragma unroll
  for (int r = 0; r < 16; ++r) {
    int row = (r & 3) + 8 * (r >> 2) + 4 * hi;
    float li = __shfl(lsum, row);
    float inv = 1.0f / li;
    u16* yp = yb + ((size_t)(b * 2048) + wq0 + row) * 2048 + h * 128 + ql;
#pragma unroll
    for (int d = 0; d < 4; ++d) yp[d * 32] = f2bf(yacc[d][r] * inv);
  }
}

// ---------------- launcher ----------------

extern "C" void kernel_launch(void* const* d_in, const int* in_sizes, int n_in,
                              void* d_out, int out_size, void* d_ws, size_t ws_size,
                              hipStream_t stream) {
  const float* x    = (const float*)d_in[0];
  const float* Wq   = (const float*)d_in[1];
  const float* Wk   = (const float*)d_in[2];
  const float* Wv   = (const float*)d_in[3];
  const float* Wo   = (const float*)d_in[4];
  const float* qn   = (const float*)d_in[5];
  const float* kn   = (const float*)d_in[6];
  const float* cosb = (const float*)d_in[7];
  const float* sinb = (const float*)d_in[8];
  float* out = (float*)d_out;
  (void)in_sizes; (void)n_in; (void)out_size; (void)ws_size;

  char* p = (char*)d_ws;
  u16*   xb   = (u16*)p;   p += (size_t)8388608 * 2;    // x bf16 [4096,2048]
  u16*   wcat = (u16*)p;   p += (size_t)6291456 * 2;    // [3072,2048]
  u16*   wob  = (u16*)p;   p += (size_t)4194304 * 2;    // [2048,2048]
  float* qkvf = (float*)p; p += (size_t)12582912 * 4;   // [4096,3072] fp32
  u16*   qh   = (u16*)p;   p += (size_t)8388608 * 2;    // [2,16,2048,128]
  u16*   kh   = (u16*)p;   p += (size_t)2097152 * 2;    // [2,4,2048,128]
  u16*   vt   = (u16*)p;   p += (size_t)2097152 * 2;    // [2,4,128,2048]
  u16*   yb   = (u16*)p;   p += (size_t)8388608 * 2;    // [4096,2048]

  cvt_f32_bf16<<<2048, 256, 0, stream>>>(x, xb, 8388608);
  build_wcat<<<2048, 256, 0, stream>>>(Wq, Wk, Wv, wcat);
  cvt_f32_bf16<<<2048, 256, 0, stream>>>(Wo, wob, 4194304);
  gemm256<<<192, 512, 0, stream>>>(xb, wcat, qkvf, 4096, 3072, 2048);
  norm_rope<<<20480, 256, 0, stream>>>(qkvf, qn, kn, cosb, sinb, qh, kh);
  v_trans<<<256, 256, 0, stream>>>(qkvf, vt);
  attn<<<512, 256, 0, stream>>>(qh, kh, vt, yb);
  gemm_bt<<<dim3(16, 32), 256, 0, stream>>>(yb, wob, out, 4096, 2048, 2048);
}

// Round 6
// 261.150 us; speedup vs baseline: 1.0451x; 1.0451x over previous
//
#include <hip/hip_runtime.h>
#include <stdint.h>

typedef unsigned short u16;
typedef __attribute__((ext_vector_type(4))) float f32x4;
typedef __attribute__((ext_vector_type(16))) float f32x16;
typedef __attribute__((ext_vector_type(8))) short bf16x8;
typedef __attribute__((ext_vector_type(4))) unsigned short u16x4;
typedef __attribute__((ext_vector_type(4))) unsigned u32x4;

static __device__ __forceinline__ u16 f2bf(float f) {
  union { float f; unsigned u; } v; v.f = f;
  unsigned r = v.u + 0x7fffu + ((v.u >> 16) & 1u);
  return (u16)(r >> 16);
}

static __device__ __forceinline__ unsigned cvtpk(float lo, float hi) {
  unsigned r;
  asm("v_cvt_pk_bf16_f32 %0, %1, %2" : "=v"(r) : "v"(lo), "v"(hi));
  return r;
}

static __device__ __forceinline__ void plane32_swap(unsigned& a, unsigned& b) {
  asm volatile("v_permlane32_swap_b32 %0, %1" : "+v"(a), "+v"(b));
}

static __device__ __forceinline__ void load_lds16(const void* g, void* l) {
  __builtin_amdgcn_global_load_lds(
      (const __attribute__((address_space(1))) void*)g,
      (__attribute__((address_space(3))) void*)l, 16, 0, 0);
}

// ---------------- conversion kernels ----------------

__global__ __launch_bounds__(256) void cvt_f32_bf16(
    const float* __restrict__ in, u16* __restrict__ out, int n) {
  int i = blockIdx.x * 256 + threadIdx.x;
  const int n4 = n >> 2;
  for (; i < n4; i += gridDim.x * 256) {
    f32x4 v = *(const f32x4*)(in + (size_t)i * 4);
    u16x4 o = { f2bf(v[0]), f2bf(v[1]), f2bf(v[2]), f2bf(v[3]) };
    *(u16x4*)(out + (size_t)i * 4) = o;
  }
}

__global__ __launch_bounds__(256) void build_wcat(
    const float* __restrict__ Wq, const float* __restrict__ Wk,
    const float* __restrict__ Wv, u16* __restrict__ out) {
  int i = blockIdx.x * 256 + threadIdx.x;
  const int n4 = 3072 * 512;
  for (; i < n4; i += gridDim.x * 256) {
    int row = i >> 9;
    int c4 = i & 511;
    const float* src;
    if (row < 2048)       src = Wq + (size_t)row * 2048;
    else if (row < 2560)  src = Wk + (size_t)(row - 2048) * 2048;
    else                  src = Wv + (size_t)(row - 2560) * 2048;
    f32x4 v = *(const f32x4*)(src + c4 * 4);
    u16x4 o = { f2bf(v[0]), f2bf(v[1]), f2bf(v[2]), f2bf(v[3]) };
    *(u16x4*)(out + (size_t)i * 4) = o;
  }
}

// ---------------- bf16 bt-GEMM (m97 structure, 128^2, XCD-localized): C = A B^T -------
// XCD x owns bm in [4x, 4x+4), bn-major inside: 4 A-panels (2 MB) stay L2-hot per XCD,
// each B-panel reused 4x back-to-back. Requires M == 4096 (32 bm panels, 4 per XCD).
__global__ __launch_bounds__(256) void gemm_bt(
    const u16* __restrict__ A, const u16* __restrict__ B,
    float* __restrict__ C, int M, int N, int K) {
  __shared__ u16 As[128 * 32];
  __shared__ u16 Bs[128 * 32];
  const int tid = threadIdx.x;
  const int lin = blockIdx.x;
  const int x = lin & 7, t = lin >> 3;   // bid%8 == XCD (round-robin dispatch)
  const int bm = x * 4 + (t & 3);
  const int bn = t >> 2;
  const int w = tid >> 6, l = tid & 63;
  const int wr = w >> 1, wc = w & 1;
  const int lr = l & 15, lg = l >> 4;
  f32x4 acc[4][4] = {};
  const int srow = tid >> 2;
  const int scol = (tid & 3) << 3;
  const u16* Ag = A + (size_t)bm * 128 * K + (size_t)srow * K + scol;
  const u16* Bg = B + (size_t)bn * 128 * K + (size_t)srow * K + scol;
  u16* Asl = As + srow * 32 + scol;
  u16* Bsl = Bs + srow * 32 + scol;
  const int nk = K >> 5;
  for (int kt = 0; kt < nk; ++kt) {
    __syncthreads();
    const int ko = kt << 5;
    load_lds16(Ag + ko, Asl);
    load_lds16(Ag + (size_t)64 * K + ko, Asl + 64 * 32);
    load_lds16(Bg + ko, Bsl);
    load_lds16(Bg + (size_t)64 * K + ko, Bsl + 64 * 32);
    __syncthreads();
    bf16x8 af[4], bfr[4];
#pragma unroll
    for (int m = 0; m < 4; ++m)
      af[m] = *(const bf16x8*)&As[(wr * 64 + m * 16 + lr) * 32 + lg * 8];
#pragma unroll
    for (int n = 0; n < 4; ++n)
      bfr[n] = *(const bf16x8*)&Bs[(wc * 64 + n * 16 + lr) * 32 + lg * 8];
#pragma unroll
    for (int m = 0; m < 4; ++m)
#pragma unroll
      for (int n = 0; n < 4; ++n)
        acc[m][n] = __builtin_amdgcn_mfma_f32_16x16x32_bf16(af[m], bfr[n], acc[m][n], 0, 0, 0);
  }
#pragma unroll
  for (int m = 0; m < 4; ++m) {
    const int row = bm * 128 + wr * 64 + m * 16 + lg * 4;
#pragma unroll
    for (int n = 0; n < 4; ++n) {
      const int col = bn * 128 + wc * 64 + n * 16 + lr;
#pragma unroll
      for (int r = 0; r < 4; ++r)
        C[(size_t)(row + r) * N + col] = acc[m][n][r];
    }
  }
}

// ---------------- per-head RMSNorm + RoPE ----------------
__global__ __launch_bounds__(256) void norm_rope(
    const float* __restrict__ qkv, const float* __restrict__ qn_w,
    const float* __restrict__ kn_w, const float* __restrict__ cosb,
    const float* __restrict__ sinb, u16* __restrict__ qhat,
    u16* __restrict__ khat) {
  const int gw = (blockIdx.x * 256 + threadIdx.x) >> 6;
  const int lane = threadIdx.x & 63;
  const int slot = gw % 20;
  const int row = gw / 20;  // b*2048 + t
  const int t = row & 2047;
  const int b = row >> 11;
  const float* src; const float* nw; u16* dst;
  bool isq = slot < 16;
  if (isq) {
    src = qkv + (size_t)row * 3072 + slot * 128;
    nw = qn_w;
    dst = qhat + ((size_t)(b * 16 + slot) * 2048 + t) * 128;
  } else {
    src = qkv + (size_t)row * 3072 + 2048 + (slot - 16) * 128;
    nw = kn_w;
    dst = khat + ((size_t)(b * 4 + (slot - 16)) * 2048 + t) * 128;
  }
  float x1 = src[lane], x2 = src[lane + 64];
  float ss = x1 * x1 + x2 * x2;
#pragma unroll
  for (int o = 32; o; o >>= 1) ss += __shfl_xor(ss, o);
  float rs = rsqrtf(ss * (1.0f / 128.0f) + 1e-6f);
  float h1 = x1 * rs * nw[lane];
  float h2 = x2 * rs * nw[lane + 64];
  float c = cosb[t * 128 + lane], s = sinb[t * 128 + lane];
  float o1 = h1 * c - h2 * s;
  float o2 = h2 * c + h1 * s;
  if (isq) { o1 *= 0.088388347648318447f; o2 *= 0.088388347648318447f; }
  dst[lane] = f2bf(o1);
  dst[lane + 64] = f2bf(o2);
}

// ---------------- V transpose: qkv fp32 [.,3072] v-cols -> vT bf16 [B,KV,D,T] ----------------
__global__ __launch_bounds__(256) void v_trans(
    const float* __restrict__ qkv, u16* __restrict__ vT) {
  __shared__ u16 st[64][130];
  const int bi = blockIdx.x;  // b*128 + kv*32 + tt
  const int tt = bi & 31;
  const int kv = (bi >> 5) & 3;
  const int b = bi >> 7;
  const int tid = threadIdx.x;
#pragma unroll
  for (int i = 0; i < 32; ++i) {
    int idx = i * 256 + tid;
    int t = idx >> 7, d = idx & 127;
    float v = qkv[(size_t)(b * 2048 + tt * 64 + t) * 3072 + 2560 + kv * 128 + d];
    st[t][d] = f2bf(v);
  }
  __syncthreads();
#pragma unroll
  for (int i = 0; i < 32; ++i) {
    int idx = i * 256 + tid;
    int d = idx >> 6, t = idx & 63;
    vT[((size_t)(b * 4 + kv) * 128 + d) * 2048 + tt * 64 + t] = st[t][d];
  }
}

// ---------------- causal GQA flash attention (8-warp uniform blocks) ----------------
// Block = 512 thr: warps 0-3 own 128-row strip s, warps 4-7 own strip 15-s -> every
// block does exactly 34 strip-tiles (uniform), each SIMD hosts one lo + one hi warp
// (role diversity for setprio), K tile staged ONCE for all 8 warps. Grid 256 = 1/CU.
// Swapped 32x32 QK^T, in-register softmax (cvt_pk + permlane32_swap), V from L2.
__global__ __launch_bounds__(512, 2) void attn(
    const u16* __restrict__ qhat, const u16* __restrict__ khat,
    const u16* __restrict__ vT, u16* __restrict__ yb) {
  __shared__ u16 Kt[2][64 * 128];
  const int bi = blockIdx.x;           // bh*8 + s
  const int s = bi & 7;
  const int bh = bi >> 3;
  const int h = bh & 15, b = bh >> 4;
  const int kvh = h >> 2;
  const int tid = threadIdx.x;
  const int w = tid >> 6, l = tid & 63;
  const int ws = w & 3;
  const int cw = (w < 4) ? s : (15 - s);  // this warp's 128-row strip
  const int ql = l & 31, hi = l >> 5;
  const int wq0 = cw * 128 + ws * 32;
  const int wq_end = wq0 + 31;
  const int qg = wq0 + ql;

  bf16x8 qf[8];
  const u16* qp = qhat + ((size_t)(b * 16 + h) * 2048 + qg) * 128 + hi * 8;
#pragma unroll
  for (int sf = 0; sf < 8; ++sf) qf[sf] = *(const bf16x8*)(qp + 16 * sf);

  f32x16 yacc[4] = {};
  float m = -1e30f, lsum = 0.f;

  const u16* Kg = khat + (size_t)(b * 4 + kvh) * 2048 * 128;
  const u16* Vg = vT + (size_t)(b * 4 + kvh) * 128 * 2048;
  const int nt = 32 - 2 * s;           // hi strip's tile count (covers lo strip too)

  // stage K tile: 512 thr x 2 x 16B = 16 KB; pre-swizzled source, linear LDS dest
  auto stageK = [&](int tile, int buf) {
#pragma unroll
    for (int j = 0; j < 2; ++j) {
      int idx = j * 512 + tid;
      int row = idx >> 4, ch = idx & 15;
      load_lds16(Kg + (size_t)(tile * 64 + row) * 128 + ((ch ^ (row & 7)) * 8),
                 &Kt[buf][idx * 8]);
    }
  };

  stageK(0, 0);
  int cur = 0;
  for (int tile = 0; tile < nt; ++tile) {
    const int kv0 = tile * 64;
    __syncthreads();  // implicit vmcnt drain: Kt[cur] ready & visible
    if (tile + 1 < nt) stageK(tile + 1, cur ^ 1);
    if (kv0 <= wq_end) {  // warp-uniform causal skip
      const u16* Vrow = Vg + (size_t)ql * 2048 + kv0 + hi * 8;
      bf16x8 va[4], vb[4];
#pragma unroll
      for (int ks = 0; ks < 4; ++ks) va[ks] = *(const bf16x8*)(Vrow + ks * 16);
#pragma unroll
      for (int ks = 0; ks < 4; ++ks) vb[ks] = *(const bf16x8*)(Vrow + 32 * 2048 + ks * 16);
      const u16* Kc = Kt[cur];
      f32x16 sacc[2] = {};
      __builtin_amdgcn_s_setprio(1);
#pragma unroll
      for (int n = 0; n < 2; ++n) {
#pragma unroll
        for (int sf = 0; sf < 8; ++sf) {
          bf16x8 kf = *(const bf16x8*)&Kc[(n * 32 + ql) * 128 + (((2 * sf + hi) ^ (l & 7)) * 8)];
          sacc[n] = __builtin_amdgcn_mfma_f32_32x32x16_bf16(kf, qf[sf], sacc[n], 0, 0, 0);
        }
      }
      __builtin_amdgcn_s_setprio(0);
      if (kv0 + 63 > wq0) {  // diagonal tile for this warp
#pragma unroll
        for (int n = 0; n < 2; ++n)
#pragma unroll
          for (int r = 0; r < 16; ++r) {
            int kv = kv0 + n * 32 + (r & 3) + 8 * (r >> 2) + 4 * hi;
            if (kv > qg) sacc[n][r] = -1e30f;
          }
      }
      float pm = -1e30f;
#pragma unroll
      for (int n = 0; n < 2; ++n)
#pragma unroll
        for (int r = 0; r < 16; ++r) pm = fmaxf(pm, sacc[n][r]);
      pm = fmaxf(pm, __shfl_xor(pm, 32));
      if (!__all(pm - m <= 8.0f)) {  // defer-max
        float mn = fmaxf(m, pm);
        float sc = __expf(m - mn);
        m = mn;
        lsum *= sc;
#pragma unroll
        for (int r = 0; r < 16; ++r) {
          int row = (r & 3) + 8 * (r >> 2) + 4 * hi;
          float scr = __shfl(sc, row);
#pragma unroll
          for (int d = 0; d < 4; ++d) yacc[d][r] *= scr;
        }
      }
      float ls = 0.f;
#pragma unroll
      for (int n = 0; n < 2; ++n)
#pragma unroll
        for (int r = 0; r < 16; ++r) {
          float e = __expf(sacc[n][r] - m);
          sacc[n][r] = e;
          ls += e;
        }
      ls += __shfl_xor(ls, 32);
      lsum += ls;
      bf16x8 pa[4];
#pragma unroll
      for (int s4 = 0; s4 < 4; ++s4) {
        const int n = s4 >> 1, R = (s4 & 1) * 8;
        unsigned P01 = cvtpk(sacc[n][R + 0], sacc[n][R + 1]);
        unsigned P23 = cvtpk(sacc[n][R + 2], sacc[n][R + 3]);
        unsigned P45 = cvtpk(sacc[n][R + 4], sacc[n][R + 5]);
        unsigned P67 = cvtpk(sacc[n][R + 6], sacc[n][R + 7]);
        plane32_swap(P01, P45);
        plane32_swap(P23, P67);
        union { u32x4 u; bf16x8 bv; } cvu;
        cvu.u[0] = P01; cvu.u[1] = P23; cvu.u[2] = P45; cvu.u[3] = P67;
        pa[s4] = cvu.bv;
      }
      __builtin_amdgcn_s_setprio(1);
#pragma unroll
      for (int ks = 0; ks < 4; ++ks)
        yacc[0] = __builtin_amdgcn_mfma_f32_32x32x16_bf16(pa[ks], va[ks], yacc[0], 0, 0, 0);
#pragma unroll
      for (int ks = 0; ks < 4; ++ks) va[ks] = *(const bf16x8*)(Vrow + 64 * 2048 + ks * 16);
#pragma unroll
      for (int ks = 0; ks < 4; ++ks)
        yacc[1] = __builtin_amdgcn_mfma_f32_32x32x16_bf16(pa[ks], vb[ks], yacc[1], 0, 0, 0);
#pragma unroll
      for (int ks = 0; ks < 4; ++ks) vb[ks] = *(const bf16x8*)(Vrow + 96 * 2048 + ks * 16);
#pragma unroll
      for (int ks = 0; ks < 4; ++ks)
        yacc[2] = __builtin_amdgcn_mfma_f32_32x32x16_bf16(pa[ks], va[ks], yacc[2], 0, 0, 0);
#pragma unroll
      for (int ks = 0; ks < 4; ++ks)
        yacc[3] = __builtin_amdgcn_mfma_f32_32x32x16_bf16(pa[ks], vb[ks], yacc[3], 0, 0, 0);
      __builtin_amdgcn_s_setprio(0);
    }
    cur ^= 1;
  }
#pragma unroll
  for (int r = 0; r < 16; ++r) {
    int row = (r & 3) + 8 * (r >> 2) + 4 * hi;
    float li = __shfl(lsum, row);
    float inv = 1.0f / li;
    u16* yp = yb + ((size_t)(b * 2048) + wq0 + row) * 2048 + h * 128 + ql;
#pragma unroll
    for (int d = 0; d < 4; ++d) yp[d * 32] = f2bf(yacc[d][r] * inv);
  }
}

// ---------------- launcher ----------------

extern "C" void kernel_launch(void* const* d_in, const int* in_sizes, int n_in,
                              void* d_out, int out_size, void* d_ws, size_t ws_size,
                              hipStream_t stream) {
  const float* x    = (const float*)d_in[0];
  const float* Wq   = (const float*)d_in[1];
  const float* Wk   = (const float*)d_in[2];
  const float* Wv   = (const float*)d_in[3];
  const float* Wo   = (const float*)d_in[4];
  const float* qn   = (const float*)d_in[5];
  const float* kn   = (const float*)d_in[6];
  const float* cosb = (const float*)d_in[7];
  const float* sinb = (const float*)d_in[8];
  float* out = (float*)d_out;
  (void)in_sizes; (void)n_in; (void)out_size; (void)ws_size;

  char* p = (char*)d_ws;
  u16*   xb   = (u16*)p;   p += (size_t)8388608 * 2;    // x bf16 [4096,2048]
  u16*   wcat = (u16*)p;   p += (size_t)6291456 * 2;    // [3072,2048]
  u16*   wob  = (u16*)p;   p += (size_t)4194304 * 2;    // [2048,2048]
  float* qkvf = (float*)p; p += (size_t)12582912 * 4;   // [4096,3072] fp32
  u16*   qh   = (u16*)p;   p += (size_t)8388608 * 2;    // [2,16,2048,128]
  u16*   kh   = (u16*)p;   p += (size_t)2097152 * 2;    // [2,4,2048,128]
  u16*   vt   = (u16*)p;   p += (size_t)2097152 * 2;    // [2,4,128,2048]
  u16*   yb   = (u16*)p;   p += (size_t)8388608 * 2;    // [4096,2048]

  cvt_f32_bf16<<<2048, 256, 0, stream>>>(x, xb, 8388608);
  build_wcat<<<2048, 256, 0, stream>>>(Wq, Wk, Wv, wcat);
  cvt_f32_bf16<<<2048, 256, 0, stream>>>(Wo, wob, 4194304);
  gemm_bt<<<768, 256, 0, stream>>>(xb, wcat, qkvf, 4096, 3072, 2048);
  norm_rope<<<20480, 256, 0, stream>>>(qkvf, qn, kn, cosb, sinb, qh, kh);
  v_trans<<<256, 256, 0, stream>>>(qkvf, vt);
  attn<<<256, 512, 0, stream>>>(qh, kh, vt, yb);
  gemm_bt<<<512, 256, 0, stream>>>(yb, wob, out, 4096, 2048, 2048);
}